// Round 4
// baseline (403.773 us; speedup 1.0000x reference)
//
#include <hip/hip_runtime.h>
#include <hip/hip_bf16.h>
#include <cstdint>
#include <cstddef>

typedef __bf16 bf16x8 __attribute__((ext_vector_type(8)));
typedef float f32x4 __attribute__((ext_vector_type(4)));

#define AS1(p) ((const __attribute__((address_space(1))) void*)(p))
#define AS3(p) ((__attribute__((address_space(3))) void*)(p))

__device__ __forceinline__ unsigned short f2bf_rne(float f) {
    union { float f; unsigned u; } c; c.f = f;
    unsigned u = c.u;
    unsigned r = (u + 0x7FFFu + ((u >> 16) & 1u)) >> 16;
    return (unsigned short)r;
}

// -------- binarize: one block per output row; sign -> bf16 bits, alpha = mean|w| --------
__global__ __launch_bounds__(256)
void binarize_k(const float* __restrict__ W, unsigned short* __restrict__ Sg,
                float* __restrict__ Alpha, int C) {
    const int r = blockIdx.x;
    const float4* w = (const float4*)(W + (size_t)r * C);
    ushort4* s = (ushort4*)(Sg + (size_t)r * C);
    const int n4 = C >> 2;
    float lsum = 0.f;
    for (int i = threadIdx.x; i < n4; i += 256) {
        float4 v = w[i];
        lsum += fabsf(v.x) + fabsf(v.y) + fabsf(v.z) + fabsf(v.w);
        ushort4 o;
        o.x = (v.x == 0.f) ? 0 : ((v.x < 0.f) ? 0xBF80 : 0x3F80);
        o.y = (v.y == 0.f) ? 0 : ((v.y < 0.f) ? 0xBF80 : 0x3F80);
        o.z = (v.z == 0.f) ? 0 : ((v.z < 0.f) ? 0xBF80 : 0x3F80);
        o.w = (v.w == 0.f) ? 0 : ((v.w < 0.f) ? 0xBF80 : 0x3F80);
        s[i] = o;
    }
    for (int o = 32; o > 0; o >>= 1) lsum += __shfl_down(lsum, o, 64);
    __shared__ float red[4];
    const int lane = threadIdx.x & 63, wid = threadIdx.x >> 6;
    if (lane == 0) red[wid] = lsum;
    __syncthreads();
    if (threadIdx.x == 0) Alpha[r] = (red[0] + red[1] + red[2] + red[3]) / (float)C;
}

// -------- fp32 -> bf16 convert (vectorized) --------
__global__ __launch_bounds__(256)
void f32_to_bf16_k(const float* __restrict__ X, unsigned short* __restrict__ Y, int n4) {
    const int stride = gridDim.x * 256;
    for (int i = blockIdx.x * 256 + threadIdx.x; i < n4; i += stride) {
        float4 v = ((const float4*)X)[i];
        ushort4 o;
        o.x = f2bf_rne(v.x); o.y = f2bf_rne(v.y);
        o.z = f2bf_rne(v.z); o.w = f2bf_rne(v.w);
        ((ushort4*)Y)[i] = o;
    }
}

// -------- binary-weight GEMM, m97 structure + conflict-free xor swizzle --------
// C[m,n] = act(alpha[n] * sum_k A[m,k]*S[n,k] + bias[n])
// A bf16 [M,K] row-major; S bf16 sign [N,K] row-major (B^T layout).
// BM=128, BN template (128 or 64), BK=64, 256 thr = 4 waves (2x2);
// per-wave 64 x BN/2 via 16x16x32 MFMA frags.
// LDS tile [R][64] with column-slot swizzle: slot holds global col-group
// (slot ^ (row&7)); staged by pre-swizzling the GLOBAL source (linear LDS
// dest for global_load_lds), read back with the same xor -> 0 bank conflicts
// (r2-verified pattern). Single-buffered 2-barrier loop; 24-32KB LDS ->
// 4-5 blocks/CU co-residency covers the barrier vmcnt drain (m97 mechanism).
template<int GELU, int BN>
__global__ __launch_bounds__(256)
void gemm_bin(const unsigned short* __restrict__ A,
              const unsigned short* __restrict__ S,
              const float* __restrict__ alpha,
              const float* __restrict__ bias,
              unsigned short* __restrict__ Obf,
              float* __restrict__ Of32,
              int M, int N, int K)
{
    constexpr int NF = BN / 64;           // B frags per wave (2 for BN=128, 1 for BN=64)... per-wave cols = BN/2
    constexpr int WN = BN / 2;            // per-wave output cols
    constexpr int NFRAG = WN / 16;        // 4 (BN=128) or 2 (BN=64)
    (void)sizeof(char[NF > 0 ? 1 : 1]);

    __shared__ __align__(16) unsigned short As[128 * 64];
    __shared__ __align__(16) unsigned short Ss[BN * 64];

    const int tid  = threadIdx.x;
    const int lane = tid & 63;
    const int wid  = tid >> 6;
    const int wr   = wid >> 1, wc = wid & 1;
    const int lr   = lane & 15;
    const int hi   = lane >> 4;           // 0..3
    const int xorv = lr & 7;

    // bijective XCD-aware block swizzle (m204 form)
    const int nbn = N / BN, nbm = M >> 7;
    const int nwg = nbm * nbn;
    const int q = nwg >> 3, r = nwg & 7;
    const int xcd = blockIdx.x & 7, loc = blockIdx.x >> 3;
    const int swz = (xcd < r ? xcd * (q + 1) : r * (q + 1) + (xcd - r) * q) + loc;
    const int bm = swz / nbn, bn = swz % nbn;

    const unsigned short* gA = A + (size_t)bm * 128 * K;
    const unsigned short* gS = S + (size_t)bn * BN * K;

    f32x4 acc[4][NFRAG] = {};

    const int nkt = K >> 6;
    for (int kt = 0; kt < nkt; ++kt) {
        const int k0 = kt << 6;
        // stage A: 128x64 -> 1024 16B units, 4 rounds; source col pre-swizzled
#pragma unroll
        for (int j = 0; j < 4; ++j) {
            const int u = j * 256 + tid;
            const int row = u >> 3;
            const int sc = ((u & 7) ^ (row & 7)) << 3;
            __builtin_amdgcn_global_load_lds(AS1(gA + (size_t)row * K + k0 + sc),
                                             AS3(&As[0] + u * 8), 16, 0, 0);
        }
        // stage B: BNx64 -> BN*8 units
#pragma unroll
        for (int j = 0; j < BN / 32; ++j) {
            const int u = j * 256 + tid;
            const int row = u >> 3;
            const int sc = ((u & 7) ^ (row & 7)) << 3;
            __builtin_amdgcn_global_load_lds(AS1(gS + (size_t)row * K + k0 + sc),
                                             AS3(&Ss[0] + u * 8), 16, 0, 0);
        }
        __syncthreads();   // compiler drains vmcnt(0); co-resident blocks cover the stall

        bf16x8 af[2][4], bf[2][NFRAG];
#pragma unroll
        for (int ks = 0; ks < 2; ++ks) {
            const int kg = ((ks << 2) + hi) ^ xorv;   // swizzled col-slot
#pragma unroll
            for (int mf = 0; mf < 4; ++mf)
                af[ks][mf] = *(const bf16x8*)(&As[0] + (wr * 64 + mf * 16 + lr) * 64 + kg * 8);
#pragma unroll
            for (int nf = 0; nf < NFRAG; ++nf)
                bf[ks][nf] = *(const bf16x8*)(&Ss[0] + (wc * WN + nf * 16 + lr) * 64 + kg * 8);
        }
#pragma unroll
        for (int ks = 0; ks < 2; ++ks)
#pragma unroll
            for (int mf = 0; mf < 4; ++mf)
#pragma unroll
                for (int nf = 0; nf < NFRAG; ++nf)
                    acc[mf][nf] = __builtin_amdgcn_mfma_f32_16x16x32_bf16(
                        af[ks][mf], bf[ks][nf], acc[mf][nf], 0, 0, 0);
        __syncthreads();
    }

    // epilogue: alpha*acc + bias, optional GELU, store
    const int col0 = bn * BN + wc * WN;
    const int row0 = bm * 128 + wr * 64;
    float al[NFRAG], bi[NFRAG];
#pragma unroll
    for (int nf = 0; nf < NFRAG; ++nf) {
        const int n = col0 + nf * 16 + lr;
        al[nf] = alpha[n];
        bi[nf] = bias[n];
    }
#pragma unroll
    for (int mf = 0; mf < 4; ++mf) {
#pragma unroll
        for (int j = 0; j < 4; ++j) {
            const int m = row0 + mf * 16 + hi * 4 + j;
#pragma unroll
            for (int nf = 0; nf < NFRAG; ++nf) {
                const int n = col0 + nf * 16 + lr;
                float v = acc[mf][nf][j] * al[nf] + bi[nf];
                if (GELU) {
                    v = 0.5f * v * (1.0f + erff(v * 0.70710678118654752f));
                    Obf[(size_t)m * N + n] = f2bf_rne(v);
                } else {
                    Of32[(size_t)m * N + n] = v;
                }
            }
        }
    }
}

extern "C" void kernel_launch(void* const* d_in, const int* in_sizes, int n_in,
                              void* d_out, int out_size, void* d_ws, size_t ws_size,
                              hipStream_t stream) {
    const float* x  = (const float*)d_in[0];
    const float* w1 = (const float*)d_in[1];
    const float* b1 = (const float*)d_in[2];
    const float* w2 = (const float*)d_in[3];
    const float* b2 = (const float*)d_in[4];
    float* out = (float*)d_out;

    const int D = 1024, H = 4096;
    const int M = in_sizes[0] / D;   // 12544 = 98*128

    char* ws = (char*)d_ws;
    size_t off = 0;
    auto alloc = [&](size_t bytes) -> void* {
        void* p = ws + off;
        off = (off + bytes + 255) & ~(size_t)255;
        return p;
    };
    unsigned short* xb = (unsigned short*)alloc((size_t)M * D * 2);   // x in bf16
    unsigned short* s1 = (unsigned short*)alloc((size_t)H * D * 2);   // sign(w1) bf16
    float*          a1 = (float*)alloc((size_t)H * 4);                // alpha1
    unsigned short* s2 = (unsigned short*)alloc((size_t)D * H * 2);   // sign(w2) bf16
    float*          a2 = (float*)alloc((size_t)D * 4);                // alpha2
    unsigned short* hb = (unsigned short*)alloc((size_t)M * H * 2);   // gelu(h) bf16

    binarize_k<<<H, 256, 0, stream>>>(w1, s1, a1, D);
    binarize_k<<<D, 256, 0, stream>>>(w2, s2, a2, H);
    f32_to_bf16_k<<<2048, 256, 0, stream>>>(x, xb, (M * D) / 4);

    // GEMM1: 98x32 = 3136 blocks (6% tail); GEMM2: 98x16 = 1568 blocks (BN=64, 14% tail)
    gemm_bin<1, 128><<<(M / 128) * (H / 128), 256, 0, stream>>>(xb, s1, a1, b1, hb, nullptr, M, H, D);
    gemm_bin<0, 64><<<(M / 128) * (D / 64), 256, 0, stream>>>(hb, s2, a2, b2, nullptr, out, M, D, H);
}